// Round 1
// baseline (411.730 us; speedup 1.0000x reference)
//
#include <hip/hip_runtime.h>
#include <hip/hip_bf16.h>

typedef unsigned short u16;
typedef __attribute__((ext_vector_type(8))) short s16x8;   // 8 bf16 (4 VGPRs) MFMA A/B frag
typedef __attribute__((ext_vector_type(4))) float f32x4;   // MFMA C/D frag

__device__ __forceinline__ u16 f2bf(float f) {
  union { float f; unsigned u; } v; v.f = f;
  unsigned r = (v.u + 0x7fffu + ((v.u >> 16) & 1u)) >> 16;  // RNE
  return (u16)r;
}
__device__ __forceinline__ float bf2f(u16 u) {
  union { unsigned u; float f; } v; v.u = ((unsigned)u) << 16;
  return v.f;
}
__device__ __forceinline__ void gld_lds16(const void* g, void* l) {
  __builtin_amdgcn_global_load_lds(
      (const __attribute__((address_space(1))) void*)g,
      (__attribute__((address_space(3))) void*)l, 16, 0, 0);
}

// ---------------- weight prep: Wkv bf16 [1024][512], WqT bf16 [512(c)][512(hd)], Wout bf16 [512][512]
__global__ void prep_w(const float* __restrict__ Wqkv, const float* __restrict__ Woutf,
                       u16* __restrict__ Wkv, u16* __restrict__ WqT, u16* __restrict__ Wout) {
  int i = blockIdx.x * 256 + threadIdx.x;          // grid 2048*256 = 524288
  Wkv[i] = f2bf(Wqkv[262144 + i]);                 // rows 512..1535 of W_qkv (k then v)
  if (i < 262144) {
    int c = i >> 9, o = i & 511;
    WqT[i]  = f2bf(Wqkv[o * 512 + c]);             // WqT[c][hd] = Wq[hd][c]
    Wout[i] = f2bf(Woutf[i]);
  }
}

// ---------------- x transpose+convert: x[b][c][l] f32 -> xt[b][l][c] bf16
__global__ __launch_bounds__(256) void prep_x(const float* __restrict__ x, u16* __restrict__ xt) {
  __shared__ float t[32][33];
  int l0 = blockIdx.x * 32, c0 = blockIdx.y * 32;
  size_t b = blockIdx.z;
  int tid = threadIdx.x;
  int r = tid >> 3, q = tid & 7;
  const float4 v = *(const float4*)(x + (b * 512 + c0 + r) * 8192 + l0 + q * 4);
  t[r][q * 4 + 0] = v.x; t[r][q * 4 + 1] = v.y;
  t[r][q * 4 + 2] = v.z; t[r][q * 4 + 3] = v.w;
  __syncthreads();
  ushort4 o;
  o.x = f2bf(t[q * 4 + 0][r]); o.y = f2bf(t[q * 4 + 1][r]);
  o.z = f2bf(t[q * 4 + 2][r]); o.w = f2bf(t[q * 4 + 3][r]);
  *(ushort4*)(xt + (b * 8192 + l0 + r) * 512 + c0 + q * 4) = o;
}

// ---------------- generic bf16 GEMM: C[m][n] = sum_k A[m][k]*BT[n][k]  (m97-style 128x128, BK=32)
// OUTF=0: bf16 out; OUTF=1: f32 out + bias[m]
template <int OUTF>
__global__ __launch_bounds__(256) void gemm_bt(
    const u16* __restrict__ A, size_t sA,
    const u16* __restrict__ BT, size_t sB,
    void* __restrict__ Cv, size_t sC,
    const float* __restrict__ bias,
    int N, int K)
{
  __shared__ u16 lsa[128 * 32];
  __shared__ u16 lsb[128 * 32];
  int tid = threadIdx.x, wid = tid >> 6, lane = tid & 63;
  int m0 = blockIdx.y << 7, n0 = blockIdx.x << 7;
  const u16* Ab = A + (size_t)blockIdx.z * sA;
  const u16* Bb = BT + (size_t)blockIdx.z * sB;
  int fr = lane & 15, kg = lane >> 4;
  int wr = wid >> 1, wc = wid & 1;
  // staging: 512 chunks of 16B per tile; chunk f -> row f>>2, k-chunk f&3; LDS byte f*16
  int f0 = tid, f1 = tid + 256;
  const u16* pA0 = Ab + (size_t)(m0 + (f0 >> 2)) * K + (f0 & 3) * 8;
  const u16* pA1 = Ab + (size_t)(m0 + (f1 >> 2)) * K + (f1 & 3) * 8;
  const u16* pB0 = Bb + (size_t)(n0 + (f0 >> 2)) * K + (f0 & 3) * 8;
  const u16* pB1 = Bb + (size_t)(n0 + (f1 >> 2)) * K + (f1 & 3) * 8;
  u16* dA0 = &lsa[wid * 512];
  u16* dA1 = &lsa[(wid + 4) * 512];
  u16* dB0 = &lsb[wid * 512];
  u16* dB1 = &lsb[(wid + 4) * 512];
  f32x4 acc[4][4] = {};
  for (int kt = 0; kt < K; kt += 32) {
    gld_lds16(pA0, dA0); gld_lds16(pA1, dA1);
    gld_lds16(pB0, dB0); gld_lds16(pB1, dB1);
    pA0 += 32; pA1 += 32; pB0 += 32; pB1 += 32;
    __syncthreads();
    s16x8 af[4], bf_[4];
#pragma unroll
    for (int mi = 0; mi < 4; ++mi)
      af[mi] = *(const s16x8*)&lsa[(wr * 64 + mi * 16 + fr) * 32 + kg * 8];
#pragma unroll
    for (int ni = 0; ni < 4; ++ni)
      bf_[ni] = *(const s16x8*)&lsb[(wc * 64 + ni * 16 + fr) * 32 + kg * 8];
#pragma unroll
    for (int mi = 0; mi < 4; ++mi)
#pragma unroll
      for (int ni = 0; ni < 4; ++ni)
        acc[mi][ni] = __builtin_amdgcn_mfma_f32_16x16x32_bf16(af[mi], bf_[ni], acc[mi][ni], 0, 0, 0);
    __syncthreads();
  }
  int r0 = m0 + wr * 64 + kg * 4;
  int c0 = n0 + wc * 64 + fr;
  if (OUTF == 0) {
    u16* C = (u16*)Cv + (size_t)blockIdx.z * sC;
#pragma unroll
    for (int mi = 0; mi < 4; ++mi)
#pragma unroll
      for (int ni = 0; ni < 4; ++ni)
#pragma unroll
        for (int j = 0; j < 4; ++j)
          C[(size_t)(r0 + mi * 16 + j) * N + (c0 + ni * 16)] = f2bf(acc[mi][ni][j]);
  } else {
    float* C = (float*)Cv + (size_t)blockIdx.z * sC;
#pragma unroll
    for (int mi = 0; mi < 4; ++mi)
#pragma unroll
      for (int j = 0; j < 4; ++j) {
        float bv = bias[r0 + mi * 16 + j];
#pragma unroll
        for (int ni = 0; ni < 4; ++ni)
          C[(size_t)(r0 + mi * 16 + j) * N + (c0 + ni * 16)] = acc[mi][ni][j] + bv;
      }
  }
}

// ---------------- context partials: per (split s, h, b): E += exp(k) @ v^T over L-slice, Z += rowsum(exp(k))
__global__ __launch_bounds__(256) void ctx_partial(const u16* __restrict__ kv,
                                                   float* __restrict__ Ep, float* __restrict__ Zp) {
  int s = blockIdx.x, h = blockIdx.y, b = blockIdx.z;
  int tid = threadIdx.x, wid = tid >> 6, lane = tid & 63;
  int fr = lane & 15, kg = lane >> 4;
  const u16* kbase = kv + ((size_t)b * 1024 + h * 64) * 8192;          // k rows
  const u16* vbase = kbase + (size_t)512 * 8192;                        // v rows
  int d = wid * 16 + fr;                                                // A-frag row for this lane
  const u16* krow = kbase + (size_t)d * 8192 + s * 2048 + kg * 8;
  f32x4 acc[4] = {};
  float z = 0.f;
  for (int l = 0; l < 2048; l += 32) {
    s16x8 kf = *(const s16x8*)(krow + l);
    s16x8 pf;
#pragma unroll
    for (int j = 0; j < 8; ++j) {
      float p = __expf(bf2f((u16)kf[j]));   // no max-subtraction: |k| <~ 6, exp safe in fp32
      z += p;
      pf[j] = (short)f2bf(p);
    }
#pragma unroll
    for (int ni = 0; ni < 4; ++ni) {
      int e = ni * 16 + fr;
      const s16x8 vf = *(const s16x8*)(vbase + (size_t)e * 8192 + s * 2048 + kg * 8 + l);
      acc[ni] = __builtin_amdgcn_mfma_f32_16x16x32_bf16(pf, vf, acc[ni], 0, 0, 0);
    }
  }
  // Z: reduce over the 4 k-groups holding the same row d (lanes differing in bits 4-5)
  z += __shfl_xor(z, 16);
  z += __shfl_xor(z, 32);
  size_t base = (size_t)(b * 8 + h) * 4 + s;
  if (kg == 0) Zp[base * 64 + d] = z;
  float* E = Ep + base * 4096;
#pragma unroll
  for (int ni = 0; ni < 4; ++ni)
#pragma unroll
    for (int j = 0; j < 4; ++j)
      E[(wid * 16 + kg * 4 + j) * 64 + ni * 16 + fr] = acc[ni][j];   // C/D: col=l&15, row=(l>>4)*4+j
}

// ---------------- reduce splits, normalize ctx, build M1[b][c][h*64+d] = sum_e Wout[c][h*64+e]*ctx[d][e]
__global__ __launch_bounds__(256) void reduce_m1(const float* __restrict__ Ep, const float* __restrict__ Zp,
                                                 const u16* __restrict__ Wout, u16* __restrict__ M1) {
  int h = blockIdx.x, b = blockIdx.y;
  __shared__ float ctx[64][68];
  __shared__ float zs[64];
  int tid = threadIdx.x;
  size_t base = (size_t)(b * 8 + h) * 4;
  const float* E = Ep + base * 4096;
  const float* Z = Zp + base * 64;
  if (tid < 64) zs[tid] = Z[tid] + Z[tid + 64] + Z[tid + 128] + Z[tid + 192];
  __syncthreads();
  for (int i = tid; i < 4096; i += 256) {
    int dd = i >> 6, e = i & 63;
    float v = E[i] + E[i + 4096] + E[i + 8192] + E[i + 12288];
    ctx[dd][e] = v / zs[dd];
  }
  __syncthreads();
  int d = tid & 63;
  for (int c = tid >> 6; c < 512; c += 4) {
    const u16* wrow = Wout + c * 512 + h * 64;
    float acc = 0.f;
#pragma unroll
    for (int e8 = 0; e8 < 8; ++e8) {
      s16x8 w8 = *(const s16x8*)(wrow + e8 * 8);
#pragma unroll
      for (int j = 0; j < 8; ++j)
        acc += bf2f((u16)w8[j]) * ctx[d][e8 * 8 + j];
    }
    M1[((size_t)b * 512 + c) * 512 + h * 64 + d] = f2bf(acc);
  }
}

extern "C" void kernel_launch(void* const* d_in, const int* in_sizes, int n_in,
                              void* d_out, int out_size, void* d_ws, size_t ws_size,
                              hipStream_t stream) {
  const float* x     = (const float*)d_in[0];   // [8,512,8192]
  const float* Wqkv  = (const float*)d_in[1];   // [1536,512]
  const float* Woutf = (const float*)d_in[2];   // [512,512]
  const float* bout  = (const float*)d_in[3];   // [512]
  char* ws = (char*)d_ws;
  u16*  xt  = (u16*)ws;                          //  64 MB  xt[b][l][c] bf16
  u16*  kv  = (u16*)(ws + 67108864);             // 128 MB  kv[b][o<1024][l] bf16 (k rows 0..511, v rows 512..1023)
  u16*  Wkv = (u16*)(ws + 201326592);            //   1 MB
  u16*  WqT = (u16*)(ws + 202375168);            // 0.5 MB
  u16*  Wo  = (u16*)(ws + 202899456);            // 0.5 MB
  u16*  M1  = (u16*)(ws + 203423744);            //   4 MB
  u16*  G   = (u16*)(ws + 207618048);            //   4 MB
  float* Ep = (float*)(ws + 211812352);          //   4 MB  E partials [b][h][4][64][64]
  float* Zp = (float*)(ws + 216006656);          //  64 KB  Z partials [b][h][4][64]

  prep_w<<<2048, 256, 0, stream>>>(Wqkv, Woutf, Wkv, WqT, Wo);
  prep_x<<<dim3(256, 16, 8), 256, 0, stream>>>(x, xt);
  // kv[b] = Wkv @ x[b] : M=1024, N=8192, K=512
  gemm_bt<0><<<dim3(64, 8, 8), 256, 0, stream>>>(Wkv, 0, xt, (size_t)8192 * 512,
                                                 kv, (size_t)1024 * 8192, nullptr, 8192, 512);
  ctx_partial<<<dim3(4, 8, 8), 256, 0, stream>>>(kv, Ep, Zp);
  reduce_m1<<<dim3(8, 8), 256, 0, stream>>>(Ep, Zp, Wo, M1);
  // G[b] = M1[b] @ Wq : M=512, N=512, K=512   (BT = WqT)
  gemm_bt<0><<<dim3(4, 4, 8), 256, 0, stream>>>(M1, (size_t)512 * 512, WqT, 0,
                                                G, (size_t)512 * 512, nullptr, 512, 512);
  // out[b] = G[b] @ x[b] + b_out : M=512, N=8192, K=512, f32 out
  gemm_bt<1><<<dim3(64, 4, 8), 256, 0, stream>>>(G, (size_t)512 * 512, xt, (size_t)8192 * 512,
                                                 d_out, (size_t)512 * 8192, bout, 8192, 512);
}

// Round 2
// 304.621 us; speedup vs baseline: 1.3516x; 1.3516x over previous
//
#include <hip/hip_runtime.h>
#include <hip/hip_bf16.h>

typedef unsigned short u16;
typedef __attribute__((ext_vector_type(8))) short s16x8;   // 8 bf16 (4 VGPRs) MFMA A/B frag
typedef __attribute__((ext_vector_type(4))) float f32x4;   // MFMA C/D frag

__device__ __forceinline__ u16 f2bf(float f) {
  union { float f; unsigned u; } v; v.f = f;
  unsigned r = (v.u + 0x7fffu + ((v.u >> 16) & 1u)) >> 16;  // RNE
  return (u16)r;
}
__device__ __forceinline__ float bf2f(u16 u) {
  union { unsigned u; float f; } v; v.u = ((unsigned)u) << 16;
  return v.f;
}
__device__ __forceinline__ void gld_lds16(const void* g, void* l) {
  __builtin_amdgcn_global_load_lds(
      (const __attribute__((address_space(1))) void*)g,
      (__attribute__((address_space(3))) void*)l, 16, 0, 0);
}

// ---------------- weight prep: Wkv bf16 [1024][512], WqT bf16 [512(c)][512(hd)], Wout bf16 [512][512]
__global__ void prep_w(const float* __restrict__ Wqkv, const float* __restrict__ Woutf,
                       u16* __restrict__ Wkv, u16* __restrict__ WqT, u16* __restrict__ Wout) {
  int i = blockIdx.x * 256 + threadIdx.x;          // grid 2048*256 = 524288
  Wkv[i] = f2bf(Wqkv[262144 + i]);                 // rows 512..1535 of W_qkv (k then v)
  if (i < 262144) {
    int c = i >> 9, o = i & 511;
    WqT[i]  = f2bf(Wqkv[o * 512 + c]);             // WqT[c][hd] = Wq[hd][c]
    Wout[i] = f2bf(Woutf[i]);
  }
}

// ---------------- x transpose+convert: x[b][c][l] f32 -> xt[b][l][c] bf16
__global__ __launch_bounds__(256) void prep_x(const float* __restrict__ x, u16* __restrict__ xt) {
  __shared__ float t[32][33];
  int l0 = blockIdx.x * 32, c0 = blockIdx.y * 32;
  size_t b = blockIdx.z;
  int tid = threadIdx.x;
  int r = tid >> 3, q = tid & 7;
  const float4 v = *(const float4*)(x + (b * 512 + c0 + r) * 8192 + l0 + q * 4);
  t[r][q * 4 + 0] = v.x; t[r][q * 4 + 1] = v.y;
  t[r][q * 4 + 2] = v.z; t[r][q * 4 + 3] = v.w;
  __syncthreads();
  ushort4 o;
  o.x = f2bf(t[q * 4 + 0][r]); o.y = f2bf(t[q * 4 + 1][r]);
  o.z = f2bf(t[q * 4 + 2][r]); o.w = f2bf(t[q * 4 + 3][r]);
  *(ushort4*)(xt + (b * 8192 + l0 + r) * 512 + c0 + q * 4) = o;
}

// ---------------- generic bf16 GEMM: C[m][n] = sum_k A[m][k]*BT[n][k]  (m97-style 128x128, BK=32)
// OUTF=0: bf16 out; OUTF=1: f32 out + bias[m]
template <int OUTF>
__global__ __launch_bounds__(256) void gemm_bt(
    const u16* __restrict__ A, size_t sA,
    const u16* __restrict__ BT, size_t sB,
    void* __restrict__ Cv, size_t sC,
    const float* __restrict__ bias,
    int N, int K)
{
  __shared__ u16 lsa[128 * 32];
  __shared__ u16 lsb[128 * 32];
  int tid = threadIdx.x, wid = tid >> 6, lane = tid & 63;
  int m0 = blockIdx.y << 7, n0 = blockIdx.x << 7;
  const u16* Ab = A + (size_t)blockIdx.z * sA;
  const u16* Bb = BT + (size_t)blockIdx.z * sB;
  int fr = lane & 15, kg = lane >> 4;
  int wr = wid >> 1, wc = wid & 1;
  // staging: 512 chunks of 16B per tile; chunk f -> row f>>2, k-chunk f&3; LDS byte f*16
  int f0 = tid, f1 = tid + 256;
  const u16* pA0 = Ab + (size_t)(m0 + (f0 >> 2)) * K + (f0 & 3) * 8;
  const u16* pA1 = Ab + (size_t)(m0 + (f1 >> 2)) * K + (f1 & 3) * 8;
  const u16* pB0 = Bb + (size_t)(n0 + (f0 >> 2)) * K + (f0 & 3) * 8;
  const u16* pB1 = Bb + (size_t)(n0 + (f1 >> 2)) * K + (f1 & 3) * 8;
  u16* dA0 = &lsa[wid * 512];
  u16* dA1 = &lsa[(wid + 4) * 512];
  u16* dB0 = &lsb[wid * 512];
  u16* dB1 = &lsb[(wid + 4) * 512];
  f32x4 acc[4][4] = {};
  for (int kt = 0; kt < K; kt += 32) {
    gld_lds16(pA0, dA0); gld_lds16(pA1, dA1);
    gld_lds16(pB0, dB0); gld_lds16(pB1, dB1);
    pA0 += 32; pA1 += 32; pB0 += 32; pB1 += 32;
    __syncthreads();
    s16x8 af[4], bf_[4];
#pragma unroll
    for (int mi = 0; mi < 4; ++mi)
      af[mi] = *(const s16x8*)&lsa[(wr * 64 + mi * 16 + fr) * 32 + kg * 8];
#pragma unroll
    for (int ni = 0; ni < 4; ++ni)
      bf_[ni] = *(const s16x8*)&lsb[(wc * 64 + ni * 16 + fr) * 32 + kg * 8];
#pragma unroll
    for (int mi = 0; mi < 4; ++mi)
#pragma unroll
      for (int ni = 0; ni < 4; ++ni)
        acc[mi][ni] = __builtin_amdgcn_mfma_f32_16x16x32_bf16(af[mi], bf_[ni], acc[mi][ni], 0, 0, 0);
    __syncthreads();
  }
  int r0 = m0 + wr * 64 + kg * 4;
  int c0 = n0 + wc * 64 + fr;
  if (OUTF == 0) {
    u16* C = (u16*)Cv + (size_t)blockIdx.z * sC;
#pragma unroll
    for (int mi = 0; mi < 4; ++mi)
#pragma unroll
      for (int ni = 0; ni < 4; ++ni)
#pragma unroll
        for (int j = 0; j < 4; ++j)
          C[(size_t)(r0 + mi * 16 + j) * N + (c0 + ni * 16)] = f2bf(acc[mi][ni][j]);
  } else {
    float* C = (float*)Cv + (size_t)blockIdx.z * sC;
#pragma unroll
    for (int mi = 0; mi < 4; ++mi)
#pragma unroll
      for (int j = 0; j < 4; ++j) {
        float bv = bias[r0 + mi * 16 + j];
#pragma unroll
        for (int ni = 0; ni < 4; ++ni)
          C[(size_t)(r0 + mi * 16 + j) * N + (c0 + ni * 16)] = acc[mi][ni][j] + bv;
      }
  }
}

// ---------------- context partials: per (split s, h, b): atomically accumulate
// E[b][h][d][e] += exp(k) @ v^T over L-slice, Z[b][h][d] += rowsum(exp(k))
#define NSPLIT 16
#define SLICE  512   // 8192 / NSPLIT
__global__ __launch_bounds__(256) void ctx_partial(const u16* __restrict__ kv,
                                                   float* __restrict__ E, float* __restrict__ Z) {
  int s = blockIdx.x, h = blockIdx.y, b = blockIdx.z;
  int tid = threadIdx.x, wid = tid >> 6, lane = tid & 63;
  int fr = lane & 15, kg = lane >> 4;
  const u16* kbase = kv + ((size_t)b * 1024 + h * 64) * 8192;          // k rows
  const u16* vbase = kbase + (size_t)512 * 8192;                        // v rows
  int d = wid * 16 + fr;                                                // A-frag row for this lane
  const u16* krow = kbase + (size_t)d * 8192 + s * SLICE + kg * 8;
  f32x4 acc[4] = {};
  float z = 0.f;
  for (int l = 0; l < SLICE; l += 32) {
    s16x8 kf = *(const s16x8*)(krow + l);
    s16x8 pf;
#pragma unroll
    for (int j = 0; j < 8; ++j) {
      float p = __expf(bf2f((u16)kf[j]));   // no max-subtraction: |k| <~ 6, exp safe in fp32
      z += p;
      pf[j] = (short)f2bf(p);
    }
#pragma unroll
    for (int ni = 0; ni < 4; ++ni) {
      int e = ni * 16 + fr;
      const s16x8 vf = *(const s16x8*)(vbase + (size_t)e * 8192 + s * SLICE + kg * 8 + l);
      acc[ni] = __builtin_amdgcn_mfma_f32_16x16x32_bf16(pf, vf, acc[ni], 0, 0, 0);
    }
  }
  // Z: reduce over the 4 k-groups holding the same row d (lanes differing in bits 4-5)
  z += __shfl_xor(z, 16);
  z += __shfl_xor(z, 32);
  size_t bh = (size_t)(b * 8 + h);
  if (kg == 0) atomicAdd(&Z[bh * 64 + d], z);
  float* Eb = E + bh * 4096;
#pragma unroll
  for (int ni = 0; ni < 4; ++ni)
#pragma unroll
    for (int j = 0; j < 4; ++j)
      atomicAdd(&Eb[(wid * 16 + kg * 4 + j) * 64 + ni * 16 + fr], acc[ni][j]);  // C/D: col=l&15, row=(l>>4)*4+j
}

// ---------------- normalize ctx + M1[b][c][h*64+d] = sum_e Wout[c][h*64+e]*ctx[d][e]
// grid (8 c-chunks, 8 h, 8 b), 256 thr. ctx in LDS [64][65] (bank = (d+e)&31 -> 2 lanes/bank, free).
__global__ __launch_bounds__(256) void m1_fused(const float* __restrict__ E, const float* __restrict__ Z,
                                                const u16* __restrict__ Wout, u16* __restrict__ M1) {
  int cb = blockIdx.x, h = blockIdx.y, b = blockIdx.z;
  __shared__ float ctx[64][65];
  __shared__ float zs[64];
  int tid = threadIdx.x;
  size_t bh = (size_t)(b * 8 + h);
  const float* Eb = E + bh * 4096;
  if (tid < 64) zs[tid] = Z[bh * 64 + tid];
  __syncthreads();
  for (int i = tid; i < 4096; i += 256)
    ctx[i >> 6][i & 63] = Eb[i] / zs[i >> 6];
  __syncthreads();
  int d = tid & 63;
  int hbase = h * 64;
  for (int ci = 0; ci < 16; ++ci) {
    int c = __builtin_amdgcn_readfirstlane(cb * 64 + (tid >> 6) + ci * 4);  // wave-uniform -> SGPR
    const u16* wrow = Wout + c * 512 + hbase;
    float a0 = 0.f, a1 = 0.f, a2 = 0.f, a3 = 0.f;
#pragma unroll
    for (int e = 0; e < 64; e += 4) {
      a0 += bf2f(wrow[e + 0]) * ctx[d][e + 0];
      a1 += bf2f(wrow[e + 1]) * ctx[d][e + 1];
      a2 += bf2f(wrow[e + 2]) * ctx[d][e + 2];
      a3 += bf2f(wrow[e + 3]) * ctx[d][e + 3];
    }
    M1[((size_t)b * 512 + c) * 512 + hbase + d] = f2bf((a0 + a1) + (a2 + a3));
  }
}

extern "C" void kernel_launch(void* const* d_in, const int* in_sizes, int n_in,
                              void* d_out, int out_size, void* d_ws, size_t ws_size,
                              hipStream_t stream) {
  const float* x     = (const float*)d_in[0];   // [8,512,8192]
  const float* Wqkv  = (const float*)d_in[1];   // [1536,512]
  const float* Woutf = (const float*)d_in[2];   // [512,512]
  const float* bout  = (const float*)d_in[3];   // [512]
  char* ws = (char*)d_ws;
  u16*  xt  = (u16*)ws;                          //  64 MB  xt[b][l][c] bf16
  u16*  kv  = (u16*)(ws + 67108864);             // 128 MB  kv[b][o<1024][l] bf16 (k rows 0..511, v rows 512..1023)
  u16*  Wkv = (u16*)(ws + 201326592);            //   1 MB
  u16*  WqT = (u16*)(ws + 202375168);            // 0.5 MB
  u16*  Wo  = (u16*)(ws + 202899456);            // 0.5 MB
  u16*  M1  = (u16*)(ws + 203423744);            //   4 MB
  u16*  G   = (u16*)(ws + 207618048);            //   4 MB
  float* E  = (float*)(ws + 211812352);          //   1 MB  E[b][h][64][64] f32 (atomic-accumulated)
  float* Z  = (float*)(ws + 212860928);          //  16 KB  Z[b][h][64] f32

  hipMemsetAsync(ws + 211812352, 0, 1048576 + 16384, stream);  // zero E+Z (ws not re-poisoned between replays)
  prep_w<<<2048, 256, 0, stream>>>(Wqkv, Woutf, Wkv, WqT, Wo);
  prep_x<<<dim3(256, 16, 8), 256, 0, stream>>>(x, xt);
  // kv[b] = Wkv @ x[b] : M=1024, N=8192, K=512
  gemm_bt<0><<<dim3(64, 8, 8), 256, 0, stream>>>(Wkv, 0, xt, (size_t)8192 * 512,
                                                 kv, (size_t)1024 * 8192, nullptr, 8192, 512);
  ctx_partial<<<dim3(NSPLIT, 8, 8), 256, 0, stream>>>(kv, E, Z);
  m1_fused<<<dim3(8, 8, 8), 256, 0, stream>>>(E, Z, Wo, M1);
  // G[b] = M1[b] @ Wq : M=512, N=512, K=512   (BT = WqT)
  gemm_bt<0><<<dim3(4, 4, 8), 256, 0, stream>>>(M1, (size_t)512 * 512, WqT, 0,
                                                G, (size_t)512 * 512, nullptr, 512, 512);
  // out[b] = G[b] @ x[b] + b_out : M=512, N=8192, K=512, f32 out
  gemm_bt<1><<<dim3(64, 4, 8), 256, 0, stream>>>(G, (size_t)512 * 512, xt, (size_t)8192 * 512,
                                                 d_out, (size_t)512 * 8192, bout, 8192, 512);
}

// Round 3
// 269.907 us; speedup vs baseline: 1.5254x; 1.1286x over previous
//
#include <hip/hip_runtime.h>
#include <hip/hip_bf16.h>

typedef unsigned short u16;
typedef __attribute__((ext_vector_type(8))) short s16x8;   // 8 bf16 (4 VGPRs) MFMA A/B frag
typedef __attribute__((ext_vector_type(4))) float f32x4;   // MFMA C/D frag

__device__ __forceinline__ u16 f2bf(float f) {
  union { float f; unsigned u; } v; v.f = f;
  unsigned r = (v.u + 0x7fffu + ((v.u >> 16) & 1u)) >> 16;  // RNE
  return (u16)r;
}
__device__ __forceinline__ float bf2f(u16 u) {
  union { unsigned u; float f; } v; v.u = ((unsigned)u) << 16;
  return v.f;
}
__device__ __forceinline__ void gld_lds16(const void* g, void* l) {
  __builtin_amdgcn_global_load_lds(
      (const __attribute__((address_space(1))) void*)g,
      (__attribute__((address_space(3))) void*)l, 16, 0, 0);
}

// ---------------- weight prep: Wkv bf16 [1024][512], WqT bf16 [512(c)][512(hd)], Wout bf16 [512][512]
__global__ void prep_w(const float* __restrict__ Wqkv, const float* __restrict__ Woutf,
                       u16* __restrict__ Wkv, u16* __restrict__ WqT, u16* __restrict__ Wout) {
  int i = blockIdx.x * 256 + threadIdx.x;          // grid 2048*256 = 524288
  Wkv[i] = f2bf(Wqkv[262144 + i]);                 // rows 512..1535 of W_qkv (k then v)
  if (i < 262144) {
    int c = i >> 9, o = i & 511;
    WqT[i]  = f2bf(Wqkv[o * 512 + c]);             // WqT[c][hd] = Wq[hd][c]
    Wout[i] = f2bf(Woutf[i]);
  }
}

// ---------------- x transpose+convert: x[b][c][l] f32 -> xt[b][l][c] bf16
__global__ __launch_bounds__(256) void prep_x(const float* __restrict__ x, u16* __restrict__ xt) {
  __shared__ float t[32][33];
  int l0 = blockIdx.x * 32, c0 = blockIdx.y * 32;
  size_t b = blockIdx.z;
  int tid = threadIdx.x;
  int r = tid >> 3, q = tid & 7;
  const float4 v = *(const float4*)(x + (b * 512 + c0 + r) * 8192 + l0 + q * 4);
  t[r][q * 4 + 0] = v.x; t[r][q * 4 + 1] = v.y;
  t[r][q * 4 + 2] = v.z; t[r][q * 4 + 3] = v.w;
  __syncthreads();
  ushort4 o;
  o.x = f2bf(t[q * 4 + 0][r]); o.y = f2bf(t[q * 4 + 1][r]);
  o.z = f2bf(t[q * 4 + 2][r]); o.w = f2bf(t[q * 4 + 3][r]);
  *(ushort4*)(xt + (b * 8192 + l0 + r) * 512 + c0 + q * 4) = o;
}

// ---------------- small-GEMM (m97-style 128x128, BK=32): C[m][n] = sum_k A[m][k]*BT[n][k], bf16 out
__global__ __launch_bounds__(256) void gemm_bt(
    const u16* __restrict__ A, size_t sA,
    const u16* __restrict__ BT, size_t sB,
    u16* __restrict__ Cv, size_t sC,
    int N, int K)
{
  __shared__ u16 lsa[128 * 32];
  __shared__ u16 lsb[128 * 32];
  int tid = threadIdx.x, wid = tid >> 6, lane = tid & 63;
  int m0 = blockIdx.y << 7, n0 = blockIdx.x << 7;
  const u16* Ab = A + (size_t)blockIdx.z * sA;
  const u16* Bb = BT + (size_t)blockIdx.z * sB;
  int fr = lane & 15, kg = lane >> 4;
  int wr = wid >> 1, wc = wid & 1;
  int f0 = tid, f1 = tid + 256;
  const u16* pA0 = Ab + (size_t)(m0 + (f0 >> 2)) * K + (f0 & 3) * 8;
  const u16* pA1 = Ab + (size_t)(m0 + (f1 >> 2)) * K + (f1 & 3) * 8;
  const u16* pB0 = Bb + (size_t)(n0 + (f0 >> 2)) * K + (f0 & 3) * 8;
  const u16* pB1 = Bb + (size_t)(n0 + (f1 >> 2)) * K + (f1 & 3) * 8;
  u16* dA0 = &lsa[wid * 512];
  u16* dA1 = &lsa[(wid + 4) * 512];
  u16* dB0 = &lsb[wid * 512];
  u16* dB1 = &lsb[(wid + 4) * 512];
  f32x4 acc[4][4] = {};
  for (int kt = 0; kt < K; kt += 32) {
    gld_lds16(pA0, dA0); gld_lds16(pA1, dA1);
    gld_lds16(pB0, dB0); gld_lds16(pB1, dB1);
    pA0 += 32; pA1 += 32; pB0 += 32; pB1 += 32;
    __syncthreads();
    s16x8 af[4], bf_[4];
#pragma unroll
    for (int mi = 0; mi < 4; ++mi)
      af[mi] = *(const s16x8*)&lsa[(wr * 64 + mi * 16 + fr) * 32 + kg * 8];
#pragma unroll
    for (int ni = 0; ni < 4; ++ni)
      bf_[ni] = *(const s16x8*)&lsb[(wc * 64 + ni * 16 + fr) * 32 + kg * 8];
#pragma unroll
    for (int mi = 0; mi < 4; ++mi)
#pragma unroll
      for (int ni = 0; ni < 4; ++ni)
        acc[mi][ni] = __builtin_amdgcn_mfma_f32_16x16x32_bf16(af[mi], bf_[ni], acc[mi][ni], 0, 0, 0);
    __syncthreads();
  }
  int r0 = m0 + wr * 64 + kg * 4;
  int c0 = n0 + wc * 64 + fr;
  u16* C = Cv + (size_t)blockIdx.z * sC;
#pragma unroll
  for (int mi = 0; mi < 4; ++mi)
#pragma unroll
    for (int ni = 0; ni < 4; ++ni)
#pragma unroll
      for (int j = 0; j < 4; ++j)
        C[(size_t)(r0 + mi * 16 + j) * N + (c0 + ni * 16)] = f2bf(acc[mi][ni][j]);
}

// ---------------- 256x256 8-phase GEMM (K=512 fixed, N-stride 8192 fixed) ----------------
// C[m][n] = sum_k A[m][k] * BT[n][k].  8 waves (2M x 4N), BK=64, 128 KiB LDS double-buffer.
// T2: per-row rotation swizzle (phys k-chunk = (kchunk + row) & 7) via pre-permuted global src,
//     linear global_load_lds dest, permuted ds_read.  T3/T4: stage tile tau+2 at ph3 (B) / ph4 (A),
//     counted vmcnt(8) once per tile.  T5: setprio around MFMA clusters.  T1: XCD chunk swizzle.
template <int OUTF>
__global__ __launch_bounds__(512, 2) void gemm8p(
    const u16* __restrict__ A, size_t sA,
    const u16* __restrict__ BT, size_t sB,
    void* __restrict__ Cv, size_t sC,
    const float* __restrict__ bias,
    int Mt, int Nt)
{
  __shared__ u16 lds[65536];   // A: slot sl at sl*16384 (half h at +h*8192); B: +32768 same layout
  const int tid = threadIdx.x, wid = tid >> 6, lane = tid & 63;
  const int wm = wid >> 2, wn = wid & 3;
  const int fr = lane & 15, kg = lane >> 4;

  const int nwg = (int)gridDim.x;
  const int bx = (int)blockIdx.x;
  const int id = (bx & 7) * (nwg >> 3) + (bx >> 3);   // bijective: nwg % 8 == 0 for all launches
  const int my = id % Mt;
  const int t2 = id / Mt;                              // M fastest: same-XCD blocks share B panel
  const int nx = t2 % Nt;
  const int z  = t2 / Nt;
  const int m0 = my << 8, n0 = nx << 8;

  const u16* Ab = A + (size_t)z * sA;
  const u16* Bb = BT + (size_t)z * sB;

  // staging geometry: wave w issue i covers phys 16B-chunks P = (w*2+i)*64 + lane of a half
  // P -> row r = P>>3, phys slot P&7 holds logical k-chunk q = ((P&7) - r) & 7
  const int r0s = wid * 16 + (lane >> 3);
  const int r1s = r0s + 8;
  const int q0 = ((lane & 7) - r0s) & 7;
  const int q1 = ((lane & 7) - r1s) & 7;
  const int dst0 = wid * 1024;          // u16: (wid*2+0)*512
  const int dst1 = wid * 1024 + 512;

  auto stage = [&](const u16* src, int row0, int kt, int base) {
    gld_lds16(src + (size_t)(row0 + r0s) * 512 + kt + q0 * 8,       &lds[base + dst0]);
    gld_lds16(src + (size_t)(row0 + r1s) * 512 + kt + q1 * 8,       &lds[base + dst1]);
    gld_lds16(src + (size_t)(row0 + 128 + r0s) * 512 + kt + q0 * 8, &lds[base + 8192 + dst0]);
    gld_lds16(src + (size_t)(row0 + 128 + r1s) * 512 + kt + q1 * 8, &lds[base + 8192 + dst1]);
  };

  // frag read: row r (r&7 == fr&7), k-chunk c=s*4+kg -> u16 idx = r*64 + ((c+r)&7)*8
  int rot[2];
  rot[0] = ((kg + fr) & 7) * 8;
  rot[1] = ((4 + kg + fr) & 7) * 8;
  const int Aoff = wm * 8192 + fr * 64;                              // + sl*16384 + mf*1024 + rot[s]
  const int Boff = 32768 + (wn >> 1) * 8192 + (wn & 1) * 4096 + fr * 64;

  f32x4 acc[8][4] = {};
  s16x8 af[4][2], bf_[4][2];

  auto tile4 = [&](int sl, int ktn, int vmode) {
    const int ab = sl * 16384 + Aoff;
    const int bb = sl * 16384 + Boff;
    // ---- phase 1: ds_read A[m0-3], B[n0-1]; MFMA m0-3 x n0-1
#pragma unroll
    for (int mf = 0; mf < 4; ++mf) {
      af[mf][0] = *(const s16x8*)&lds[ab + mf * 1024 + rot[0]];
      af[mf][1] = *(const s16x8*)&lds[ab + mf * 1024 + rot[1]];
    }
#pragma unroll
    for (int nf = 0; nf < 2; ++nf) {
      bf_[nf][0] = *(const s16x8*)&lds[bb + nf * 1024 + rot[0]];
      bf_[nf][1] = *(const s16x8*)&lds[bb + nf * 1024 + rot[1]];
    }
    __builtin_amdgcn_s_barrier();
    asm volatile("s_waitcnt lgkmcnt(0)" ::: "memory");
    __builtin_amdgcn_sched_barrier(0);
    __builtin_amdgcn_s_setprio(1);
#pragma unroll
    for (int mf = 0; mf < 4; ++mf)
#pragma unroll
      for (int nf = 0; nf < 2; ++nf) {
        acc[mf][nf] = __builtin_amdgcn_mfma_f32_16x16x32_bf16(af[mf][0], bf_[nf][0], acc[mf][nf], 0, 0, 0);
        acc[mf][nf] = __builtin_amdgcn_mfma_f32_16x16x32_bf16(af[mf][1], bf_[nf][1], acc[mf][nf], 0, 0, 0);
      }
    __builtin_amdgcn_s_setprio(0);
    __builtin_amdgcn_s_barrier();
    __builtin_amdgcn_sched_barrier(0);
    // ---- phase 2: ds_read B[n2-3]; MFMA m0-3 x n2-3
#pragma unroll
    for (int nf = 2; nf < 4; ++nf) {
      bf_[nf][0] = *(const s16x8*)&lds[bb + nf * 1024 + rot[0]];
      bf_[nf][1] = *(const s16x8*)&lds[bb + nf * 1024 + rot[1]];
    }
    __builtin_amdgcn_s_barrier();
    asm volatile("s_waitcnt lgkmcnt(0)" ::: "memory");
    __builtin_amdgcn_sched_barrier(0);
    __builtin_amdgcn_s_setprio(1);
#pragma unroll
    for (int mf = 0; mf < 4; ++mf)
#pragma unroll
      for (int nf = 2; nf < 4; ++nf) {
        acc[mf][nf] = __builtin_amdgcn_mfma_f32_16x16x32_bf16(af[mf][0], bf_[nf][0], acc[mf][nf], 0, 0, 0);
        acc[mf][nf] = __builtin_amdgcn_mfma_f32_16x16x32_bf16(af[mf][1], bf_[nf][1], acc[mf][nf], 0, 0, 0);
      }
    __builtin_amdgcn_s_setprio(0);
    __builtin_amdgcn_s_barrier();
    __builtin_amdgcn_sched_barrier(0);
    // ---- phase 3: ds_read A[m4-7]; stage B(tile tau+2) [B slot last read in ph2]; MFMA m4-7 x n0-1
#pragma unroll
    for (int mf = 0; mf < 4; ++mf) {
      af[mf][0] = *(const s16x8*)&lds[ab + (mf + 4) * 1024 + rot[0]];
      af[mf][1] = *(const s16x8*)&lds[ab + (mf + 4) * 1024 + rot[1]];
    }
    if (vmode == 8) stage(Bb, n0, ktn, 32768 + sl * 16384);
    __builtin_amdgcn_s_barrier();
    asm volatile("s_waitcnt lgkmcnt(0)" ::: "memory");
    __builtin_amdgcn_sched_barrier(0);
    __builtin_amdgcn_s_setprio(1);
#pragma unroll
    for (int mf = 0; mf < 4; ++mf)
#pragma unroll
      for (int nf = 0; nf < 2; ++nf) {
        acc[mf + 4][nf] = __builtin_amdgcn_mfma_f32_16x16x32_bf16(af[mf][0], bf_[nf][0], acc[mf + 4][nf], 0, 0, 0);
        acc[mf + 4][nf] = __builtin_amdgcn_mfma_f32_16x16x32_bf16(af[mf][1], bf_[nf][1], acc[mf + 4][nf], 0, 0, 0);
      }
    __builtin_amdgcn_s_setprio(0);
    __builtin_amdgcn_s_barrier();
    __builtin_amdgcn_sched_barrier(0);
    // ---- phase 4: stage A(tau+2) [A slot last read in ph3]; vmcnt; MFMA m4-7 x n2-3
    if (vmode == 8) stage(Ab, m0, ktn, sl * 16384);
    if (vmode == 8)      { asm volatile("s_waitcnt vmcnt(8)" ::: "memory"); }
    else if (vmode == 0) { asm volatile("s_waitcnt vmcnt(0)" ::: "memory"); }
    __builtin_amdgcn_sched_barrier(0);
    __builtin_amdgcn_s_barrier();
    __builtin_amdgcn_sched_barrier(0);
    __builtin_amdgcn_s_setprio(1);
#pragma unroll
    for (int mf = 0; mf < 4; ++mf)
#pragma unroll
      for (int nf = 2; nf < 4; ++nf) {
        acc[mf + 4][nf] = __builtin_amdgcn_mfma_f32_16x16x32_bf16(af[mf][0], bf_[nf][0], acc[mf + 4][nf], 0, 0, 0);
        acc[mf + 4][nf] = __builtin_amdgcn_mfma_f32_16x16x32_bf16(af[mf][1], bf_[nf][1], acc[mf + 4][nf], 0, 0, 0);
      }
    __builtin_amdgcn_s_setprio(0);
    __builtin_amdgcn_s_barrier();
    __builtin_amdgcn_sched_barrier(0);
  };

  // prologue: stage tiles 0 and 1 fully; wait for tile 0 (8 loads of tile 1 in flight)
  stage(Ab, m0, 0, 0);
  stage(Bb, n0, 0, 32768);
  stage(Ab, m0, 64, 16384);
  stage(Bb, n0, 64, 32768 + 16384);
  asm volatile("s_waitcnt vmcnt(8)" ::: "memory");
  __builtin_amdgcn_s_barrier();
  __builtin_amdgcn_sched_barrier(0);
  for (int tau = 0; tau < 6; ++tau)
    tile4(tau & 1, (tau + 2) * 64, 8);
  tile4(0, 0, 0);    // tau=6: no stage, drain vmcnt(0) so tile 7 is resident
  tile4(1, 0, -1);   // tau=7: no stage, no wait

  // epilogue: C/D frag layout col = lane&15, row = (lane>>4)*4 + j
  const int rbase = m0 + wm * 128 + kg * 4;
  const int cbase = n0 + wn * 64 + fr;
  if (OUTF == 0) {
    u16* C = (u16*)Cv + (size_t)z * sC;
#pragma unroll
    for (int mf = 0; mf < 8; ++mf)
#pragma unroll
      for (int nf = 0; nf < 4; ++nf)
#pragma unroll
        for (int j = 0; j < 4; ++j)
          C[(size_t)(rbase + mf * 16 + j) * 8192 + cbase + nf * 16] = f2bf(acc[mf][nf][j]);
  } else {
    float* C = (float*)Cv + (size_t)z * sC;
#pragma unroll
    for (int mf = 0; mf < 8; ++mf)
#pragma unroll
      for (int j = 0; j < 4; ++j) {
        float bv = bias[rbase + mf * 16 + j];
#pragma unroll
        for (int nf = 0; nf < 4; ++nf)
          C[(size_t)(rbase + mf * 16 + j) * 8192 + cbase + nf * 16] = acc[mf][nf][j] + bv;
      }
  }
}

// ---------------- context partials: per (split s, h, b): atomically accumulate
// E[b][h][d][e] += exp(k) @ v^T over L-slice, Z[b][h][d] += rowsum(exp(k))
#define NSPLIT 16
#define SLICE  512   // 8192 / NSPLIT
__global__ __launch_bounds__(256) void ctx_partial(const u16* __restrict__ kv,
                                                   float* __restrict__ E, float* __restrict__ Z) {
  int s = blockIdx.x, h = blockIdx.y, b = blockIdx.z;
  int tid = threadIdx.x, wid = tid >> 6, lane = tid & 63;
  int fr = lane & 15, kg = lane >> 4;
  const u16* kbase = kv + ((size_t)b * 1024 + h * 64) * 8192;          // k rows
  const u16* vbase = kbase + (size_t)512 * 8192;                        // v rows
  int d = wid * 16 + fr;                                                // A-frag row for this lane
  const u16* krow = kbase + (size_t)d * 8192 + s * SLICE + kg * 8;
  f32x4 acc[4] = {};
  float z = 0.f;
  for (int l = 0; l < SLICE; l += 32) {
    s16x8 kf = *(const s16x8*)(krow + l);
    s16x8 pf;
#pragma unroll
    for (int j = 0; j < 8; ++j) {
      float p = __expf(bf2f((u16)kf[j]));   // no max-subtraction: |k| <~ 6, exp safe in fp32
      z += p;
      pf[j] = (short)f2bf(p);
    }
#pragma unroll
    for (int ni = 0; ni < 4; ++ni) {
      int e = ni * 16 + fr;
      const s16x8 vf = *(const s16x8*)(vbase + (size_t)e * 8192 + s * SLICE + kg * 8 + l);
      acc[ni] = __builtin_amdgcn_mfma_f32_16x16x32_bf16(pf, vf, acc[ni], 0, 0, 0);
    }
  }
  z += __shfl_xor(z, 16);
  z += __shfl_xor(z, 32);
  size_t bh = (size_t)(b * 8 + h);
  if (kg == 0) atomicAdd(&Z[bh * 64 + d], z);
  float* Eb = E + bh * 4096;
#pragma unroll
  for (int ni = 0; ni < 4; ++ni)
#pragma unroll
    for (int j = 0; j < 4; ++j)
      atomicAdd(&Eb[(wid * 16 + kg * 4 + j) * 64 + ni * 16 + fr], acc[ni][j]);  // C/D: col=l&15, row=(l>>4)*4+j
}

// ---------------- normalize ctx + M1[b][c][h*64+d] = sum_e Wout[c][h*64+e]*ctx[d][e]
__global__ __launch_bounds__(256) void m1_fused(const float* __restrict__ E, const float* __restrict__ Z,
                                                const u16* __restrict__ Wout, u16* __restrict__ M1) {
  int cb = blockIdx.x, h = blockIdx.y, b = blockIdx.z;
  __shared__ float ctx[64][65];
  __shared__ float zs[64];
  int tid = threadIdx.x;
  size_t bh = (size_t)(b * 8 + h);
  const float* Eb = E + bh * 4096;
  if (tid < 64) zs[tid] = Z[bh * 64 + tid];
  __syncthreads();
  for (int i = tid; i < 4096; i += 256)
    ctx[i >> 6][i & 63] = Eb[i] / zs[i >> 6];
  __syncthreads();
  int d = tid & 63;
  int hbase = h * 64;
  for (int ci = 0; ci < 16; ++ci) {
    int c = __builtin_amdgcn_readfirstlane(cb * 64 + (tid >> 6) + ci * 4);  // wave-uniform -> SGPR
    const u16* wrow = Wout + c * 512 + hbase;
    float a0 = 0.f, a1 = 0.f, a2 = 0.f, a3 = 0.f;
#pragma unroll
    for (int e = 0; e < 64; e += 4) {
      a0 += bf2f(wrow[e + 0]) * ctx[d][e + 0];
      a1 += bf2f(wrow[e + 1]) * ctx[d][e + 1];
      a2 += bf2f(wrow[e + 2]) * ctx[d][e + 2];
      a3 += bf2f(wrow[e + 3]) * ctx[d][e + 3];
    }
    M1[((size_t)b * 512 + c) * 512 + hbase + d] = f2bf((a0 + a1) + (a2 + a3));
  }
}

extern "C" void kernel_launch(void* const* d_in, const int* in_sizes, int n_in,
                              void* d_out, int out_size, void* d_ws, size_t ws_size,
                              hipStream_t stream) {
  const float* x     = (const float*)d_in[0];   // [8,512,8192]
  const float* Wqkv  = (const float*)d_in[1];   // [1536,512]
  const float* Woutf = (const float*)d_in[2];   // [512,512]
  const float* bout  = (const float*)d_in[3];   // [512]
  char* ws = (char*)d_ws;
  u16*  xt  = (u16*)ws;                          //  64 MB  xt[b][l][c] bf16
  u16*  kv  = (u16*)(ws + 67108864);             // 128 MB  kv[b][o<1024][l] bf16 (k rows 0..511, v rows 512..1023)
  u16*  Wkv = (u16*)(ws + 201326592);            //   1 MB
  u16*  WqT = (u16*)(ws + 202375168);            // 0.5 MB
  u16*  Wo  = (u16*)(ws + 202899456);            // 0.5 MB
  u16*  M1  = (u16*)(ws + 203423744);            //   4 MB
  u16*  G   = (u16*)(ws + 207618048);            //   4 MB
  float* E  = (float*)(ws + 211812352);          //   1 MB  E[b][h][64][64] f32 (atomic-accumulated)
  float* Z  = (float*)(ws + 212860928);          //  16 KB  Z[b][h][64] f32

  hipMemsetAsync(ws + 211812352, 0, 1048576 + 16384, stream);  // zero E+Z (ws not re-poisoned between replays)
  prep_w<<<2048, 256, 0, stream>>>(Wqkv, Woutf, Wkv, WqT, Wo);
  prep_x<<<dim3(256, 16, 8), 256, 0, stream>>>(x, xt);
  // kv[b] = Wkv @ x[b] : M=1024, N=8192, K=512  (256² 8-phase; grid = Nt*Mt*B = 32*4*8)
  gemm8p<0><<<1024, 512, 0, stream>>>(Wkv, 0, xt, (size_t)8192 * 512,
                                      kv, (size_t)1024 * 8192, nullptr, 4, 32);
  ctx_partial<<<dim3(NSPLIT, 8, 8), 256, 0, stream>>>(kv, E, Z);
  m1_fused<<<dim3(8, 8, 8), 256, 0, stream>>>(E, Z, Wo, M1);
  // G[b] = M1[b] @ Wq : M=512, N=512, K=512   (small: old 128² kernel)
  gemm_bt<<<dim3(4, 4, 8), 256, 0, stream>>>(M1, (size_t)512 * 512, WqT, 0,
                                             G, (size_t)512 * 512, 512, 512);
  // out[b] = G[b] @ x[b] + b_out : M=512, N=8192, K=512, f32 out + bias  (grid = 32*2*8)
  gemm8p<1><<<512, 512, 0, stream>>>(G, (size_t)512 * 512, xt, (size_t)8192 * 512,
                                     d_out, (size_t)512 * 8192, bout, 2, 32);
}

// Round 4
// 269.156 us; speedup vs baseline: 1.5297x; 1.0028x over previous
//
#include <hip/hip_runtime.h>
#include <hip/hip_bf16.h>

typedef unsigned short u16;
typedef __attribute__((ext_vector_type(8))) short s16x8;   // 8 bf16 (4 VGPRs) MFMA A/B frag
typedef __attribute__((ext_vector_type(4))) float f32x4;   // MFMA C/D frag

__device__ __forceinline__ u16 f2bf(float f) {
  union { float f; unsigned u; } v; v.f = f;
  unsigned r = (v.u + 0x7fffu + ((v.u >> 16) & 1u)) >> 16;  // RNE
  return (u16)r;
}
__device__ __forceinline__ float bf2f(u16 u) {
  union { unsigned u; float f; } v; v.u = ((unsigned)u) << 16;
  return v.f;
}
__device__ __forceinline__ void gld_lds16(const void* g, void* l) {
  __builtin_amdgcn_global_load_lds(
      (const __attribute__((address_space(1))) void*)g,
      (__attribute__((address_space(3))) void*)l, 16, 0, 0);
}

// ---------------- weight prep: Wkv bf16 [1024][512], WqT bf16 [512(c)][512(hd)], Wout bf16 [512][512]
__global__ void prep_w(const float* __restrict__ Wqkv, const float* __restrict__ Woutf,
                       u16* __restrict__ Wkv, u16* __restrict__ WqT, u16* __restrict__ Wout) {
  int i = blockIdx.x * 256 + threadIdx.x;          // grid 2048*256 = 524288
  Wkv[i] = f2bf(Wqkv[262144 + i]);                 // rows 512..1535 of W_qkv (k then v)
  if (i < 262144) {
    int c = i >> 9, o = i & 511;
    WqT[i]  = f2bf(Wqkv[o * 512 + c]);             // WqT[c][hd] = Wq[hd][c]
    Wout[i] = f2bf(Woutf[i]);
  }
}

// ---------------- x transpose+convert: x[b][c][l] f32 -> xt[b][l][c] bf16
__global__ __launch_bounds__(256) void prep_x(const float* __restrict__ x, u16* __restrict__ xt) {
  __shared__ float t[32][33];
  int l0 = blockIdx.x * 32, c0 = blockIdx.y * 32;
  size_t b = blockIdx.z;
  int tid = threadIdx.x;
  int r = tid >> 3, q = tid & 7;
  const float4 v = *(const float4*)(x + (b * 512 + c0 + r) * 8192 + l0 + q * 4);
  t[r][q * 4 + 0] = v.x; t[r][q * 4 + 1] = v.y;
  t[r][q * 4 + 2] = v.z; t[r][q * 4 + 3] = v.w;
  __syncthreads();
  ushort4 o;
  o.x = f2bf(t[q * 4 + 0][r]); o.y = f2bf(t[q * 4 + 1][r]);
  o.z = f2bf(t[q * 4 + 2][r]); o.w = f2bf(t[q * 4 + 3][r]);
  *(ushort4*)(xt + (b * 8192 + l0 + r) * 512 + c0 + q * 4) = o;
}

// ---------------- small-GEMM (m97-style 128x128, BK=32): C[m][n] = sum_k A[m][k]*BT[n][k], bf16 out
__global__ __launch_bounds__(256) void gemm_bt(
    const u16* __restrict__ A, size_t sA,
    const u16* __restrict__ BT, size_t sB,
    u16* __restrict__ Cv, size_t sC,
    int N, int K)
{
  __shared__ u16 lsa[128 * 32];
  __shared__ u16 lsb[128 * 32];
  int tid = threadIdx.x, wid = tid >> 6, lane = tid & 63;
  int m0 = blockIdx.y << 7, n0 = blockIdx.x << 7;
  const u16* Ab = A + (size_t)blockIdx.z * sA;
  const u16* Bb = BT + (size_t)blockIdx.z * sB;
  int fr = lane & 15, kg = lane >> 4;
  int wr = wid >> 1, wc = wid & 1;
  int f0 = tid, f1 = tid + 256;
  const u16* pA0 = Ab + (size_t)(m0 + (f0 >> 2)) * K + (f0 & 3) * 8;
  const u16* pA1 = Ab + (size_t)(m0 + (f1 >> 2)) * K + (f1 & 3) * 8;
  const u16* pB0 = Bb + (size_t)(n0 + (f0 >> 2)) * K + (f0 & 3) * 8;
  const u16* pB1 = Bb + (size_t)(n0 + (f1 >> 2)) * K + (f1 & 3) * 8;
  u16* dA0 = &lsa[wid * 512];
  u16* dA1 = &lsa[(wid + 4) * 512];
  u16* dB0 = &lsb[wid * 512];
  u16* dB1 = &lsb[(wid + 4) * 512];
  f32x4 acc[4][4] = {};
  for (int kt = 0; kt < K; kt += 32) {
    gld_lds16(pA0, dA0); gld_lds16(pA1, dA1);
    gld_lds16(pB0, dB0); gld_lds16(pB1, dB1);
    pA0 += 32; pA1 += 32; pB0 += 32; pB1 += 32;
    __syncthreads();
    s16x8 af[4], bf_[4];
#pragma unroll
    for (int mi = 0; mi < 4; ++mi)
      af[mi] = *(const s16x8*)&lsa[(wr * 64 + mi * 16 + fr) * 32 + kg * 8];
#pragma unroll
    for (int ni = 0; ni < 4; ++ni)
      bf_[ni] = *(const s16x8*)&lsb[(wc * 64 + ni * 16 + fr) * 32 + kg * 8];
#pragma unroll
    for (int mi = 0; mi < 4; ++mi)
#pragma unroll
      for (int ni = 0; ni < 4; ++ni)
        acc[mi][ni] = __builtin_amdgcn_mfma_f32_16x16x32_bf16(af[mi], bf_[ni], acc[mi][ni], 0, 0, 0);
    __syncthreads();
  }
  int r0 = m0 + wr * 64 + kg * 4;
  int c0 = n0 + wc * 64 + fr;
  u16* C = Cv + (size_t)blockIdx.z * sC;
#pragma unroll
  for (int mi = 0; mi < 4; ++mi)
#pragma unroll
    for (int ni = 0; ni < 4; ++ni)
#pragma unroll
      for (int j = 0; j < 4; ++j)
        C[(size_t)(r0 + mi * 16 + j) * N + (c0 + ni * 16)] = f2bf(acc[mi][ni][j]);
}

// ---------------- 256x256 8-phase GEMM (K=512 fixed, N-stride 8192 fixed) ----------------
// C[m][n] = sum_k A[m][k] * BT[n][k].  8 waves (2M x 4N), BK=64, 128 KiB LDS double-buffer.
// T2: per-row rotation swizzle (phys k-chunk = (kchunk + row) & 7) via pre-permuted global src,
//     linear global_load_lds dest, permuted ds_read.  T3/T4: stage tile tau+2 at ph3 (B) / ph4 (A),
//     counted vmcnt(8) once per tile.  T5: setprio around MFMA clusters.  T1: XCD chunk swizzle.
// R4: NO sched_barrier(0), NO asm lgkmcnt -- ds_reads are compiler-visible, the compiler emits
//     fine-grained lgkmcnt itself (m97 r109); hand-pinning was the m141 regression (510-TF regime).
template <int OUTF>
__global__ __launch_bounds__(512, 2) void gemm8p(
    const u16* __restrict__ A, size_t sA,
    const u16* __restrict__ BT, size_t sB,
    void* __restrict__ Cv, size_t sC,
    const float* __restrict__ bias,
    int Mt, int Nt)
{
  __shared__ u16 lds[65536];   // A: slot sl at sl*16384 (half h at +h*8192); B: +32768 same layout
  const int tid = threadIdx.x, wid = tid >> 6, lane = tid & 63;
  const int wm = wid >> 2, wn = wid & 3;
  const int fr = lane & 15, kg = lane >> 4;

  const int nwg = (int)gridDim.x;
  const int bx = (int)blockIdx.x;
  const int id = (bx & 7) * (nwg >> 3) + (bx >> 3);   // bijective: nwg % 8 == 0 for all launches
  const int my = id % Mt;
  const int t2 = id / Mt;                              // M fastest: same-XCD blocks share B panel
  const int nx = t2 % Nt;
  const int z  = t2 / Nt;
  const int m0 = my << 8, n0 = nx << 8;

  const u16* Ab = A + (size_t)z * sA;
  const u16* Bb = BT + (size_t)z * sB;

  // staging geometry: wave w issue i covers phys 16B-chunks P = (w*2+i)*64 + lane of a half
  // P -> row r = P>>3, phys slot P&7 holds logical k-chunk q = ((P&7) - r) & 7
  const int r0s = wid * 16 + (lane >> 3);
  const int r1s = r0s + 8;
  const int q0 = ((lane & 7) - r0s) & 7;
  const int q1 = ((lane & 7) - r1s) & 7;
  const int dst0 = wid * 1024;          // u16: (wid*2+0)*512
  const int dst1 = wid * 1024 + 512;

  auto stage = [&](const u16* src, int row0, int kt, int base) {
    gld_lds16(src + (size_t)(row0 + r0s) * 512 + kt + q0 * 8,       &lds[base + dst0]);
    gld_lds16(src + (size_t)(row0 + r1s) * 512 + kt + q1 * 8,       &lds[base + dst1]);
    gld_lds16(src + (size_t)(row0 + 128 + r0s) * 512 + kt + q0 * 8, &lds[base + 8192 + dst0]);
    gld_lds16(src + (size_t)(row0 + 128 + r1s) * 512 + kt + q1 * 8, &lds[base + 8192 + dst1]);
  };

  // frag read: row r (r&7 == fr&7), k-chunk c=s*4+kg -> u16 idx = r*64 + ((c+r)&7)*8
  int rot[2];
  rot[0] = ((kg + fr) & 7) * 8;
  rot[1] = ((4 + kg + fr) & 7) * 8;
  const int Aoff = wm * 8192 + fr * 64;                              // + sl*16384 + mf*1024 + rot[s]
  const int Boff = 32768 + (wn >> 1) * 8192 + (wn & 1) * 4096 + fr * 64;

  f32x4 acc[8][4] = {};
  s16x8 af[4][2], bf_[4][2];

  auto tile4 = [&](int sl, int ktn, int vmode) {
    const int ab = sl * 16384 + Aoff;
    const int bb = sl * 16384 + Boff;
    // ---- phase 1: ds_read A[m0-3], B[n0-1]; MFMA m0-3 x n0-1
#pragma unroll
    for (int mf = 0; mf < 4; ++mf) {
      af[mf][0] = *(const s16x8*)&lds[ab + mf * 1024 + rot[0]];
      af[mf][1] = *(const s16x8*)&lds[ab + mf * 1024 + rot[1]];
    }
#pragma unroll
    for (int nf = 0; nf < 2; ++nf) {
      bf_[nf][0] = *(const s16x8*)&lds[bb + nf * 1024 + rot[0]];
      bf_[nf][1] = *(const s16x8*)&lds[bb + nf * 1024 + rot[1]];
    }
    __builtin_amdgcn_s_barrier();
    __builtin_amdgcn_s_setprio(1);
#pragma unroll
    for (int mf = 0; mf < 4; ++mf)
#pragma unroll
      for (int nf = 0; nf < 2; ++nf) {
        acc[mf][nf] = __builtin_amdgcn_mfma_f32_16x16x32_bf16(af[mf][0], bf_[nf][0], acc[mf][nf], 0, 0, 0);
        acc[mf][nf] = __builtin_amdgcn_mfma_f32_16x16x32_bf16(af[mf][1], bf_[nf][1], acc[mf][nf], 0, 0, 0);
      }
    __builtin_amdgcn_s_setprio(0);
    __builtin_amdgcn_s_barrier();
    // ---- phase 2: ds_read B[n2-3]; MFMA m0-3 x n2-3
#pragma unroll
    for (int nf = 2; nf < 4; ++nf) {
      bf_[nf][0] = *(const s16x8*)&lds[bb + nf * 1024 + rot[0]];
      bf_[nf][1] = *(const s16x8*)&lds[bb + nf * 1024 + rot[1]];
    }
    __builtin_amdgcn_s_barrier();
    __builtin_amdgcn_s_setprio(1);
#pragma unroll
    for (int mf = 0; mf < 4; ++mf)
#pragma unroll
      for (int nf = 2; nf < 4; ++nf) {
        acc[mf][nf] = __builtin_amdgcn_mfma_f32_16x16x32_bf16(af[mf][0], bf_[nf][0], acc[mf][nf], 0, 0, 0);
        acc[mf][nf] = __builtin_amdgcn_mfma_f32_16x16x32_bf16(af[mf][1], bf_[nf][1], acc[mf][nf], 0, 0, 0);
      }
    __builtin_amdgcn_s_setprio(0);
    __builtin_amdgcn_s_barrier();
    // ---- phase 3: stage B(tile tau+2) [B last read in ph2]; ds_read A[m4-7]; MFMA m4-7 x n0-1
    if (vmode == 8) stage(Bb, n0, ktn, 32768 + sl * 16384);
#pragma unroll
    for (int mf = 0; mf < 4; ++mf) {
      af[mf][0] = *(const s16x8*)&lds[ab + (mf + 4) * 1024 + rot[0]];
      af[mf][1] = *(const s16x8*)&lds[ab + (mf + 4) * 1024 + rot[1]];
    }
    __builtin_amdgcn_s_barrier();
    __builtin_amdgcn_s_setprio(1);
#pragma unroll
    for (int mf = 0; mf < 4; ++mf)
#pragma unroll
      for (int nf = 0; nf < 2; ++nf) {
        acc[mf + 4][nf] = __builtin_amdgcn_mfma_f32_16x16x32_bf16(af[mf][0], bf_[nf][0], acc[mf + 4][nf], 0, 0, 0);
        acc[mf + 4][nf] = __builtin_amdgcn_mfma_f32_16x16x32_bf16(af[mf][1], bf_[nf][1], acc[mf + 4][nf], 0, 0, 0);
      }
    __builtin_amdgcn_s_setprio(0);
    __builtin_amdgcn_s_barrier();
    // ---- phase 4: stage A(tau+2) [A last read in ph3]; vmcnt; MFMA m4-7 x n2-3
    if (vmode == 8) stage(Ab, m0, ktn, sl * 16384);
    if (vmode == 8)      { asm volatile("s_waitcnt vmcnt(8)" ::: "memory"); }
    else if (vmode == 0) { asm volatile("s_waitcnt vmcnt(0)" ::: "memory"); }
    __builtin_amdgcn_s_barrier();
    __builtin_amdgcn_s_setprio(1);
#pragma unroll
    for (int mf = 0; mf < 4; ++mf)
#pragma unroll
      for (int nf = 2; nf < 4; ++nf) {
        acc[mf + 4][nf] = __builtin_amdgcn_mfma_f32_16x16x32_bf16(af[mf][0], bf_[nf][0], acc[mf + 4][nf], 0, 0, 0);
        acc[mf + 4][nf] = __builtin_amdgcn_mfma_f32_16x16x32_bf16(af[mf][1], bf_[nf][1], acc[mf + 4][nf], 0, 0, 0);
      }
    __builtin_amdgcn_s_setprio(0);
    __builtin_amdgcn_s_barrier();
  };

  // prologue: stage tiles 0 and 1 fully; wait for tile 0 (8 loads of tile 1 in flight)
  stage(Ab, m0, 0, 0);
  stage(Bb, n0, 0, 32768);
  stage(Ab, m0, 64, 16384);
  stage(Bb, n0, 64, 32768 + 16384);
  asm volatile("s_waitcnt vmcnt(8)" ::: "memory");
  __builtin_amdgcn_s_barrier();
  for (int tau = 0; tau < 6; ++tau)
    tile4(tau & 1, (tau + 2) * 64, 8);
  tile4(0, 0, 0);    // tau=6: no stage, drain vmcnt(0) so tile 7 is resident
  tile4(1, 0, -1);   // tau=7: no stage, no wait

  // epilogue: C/D frag layout col = lane&15, row = (lane>>4)*4 + j
  const int rbase = m0 + wm * 128 + kg * 4;
  const int cbase = n0 + wn * 64 + fr;
  if (OUTF == 0) {
    u16* C = (u16*)Cv + (size_t)z * sC;
#pragma unroll
    for (int mf = 0; mf < 8; ++mf)
#pragma unroll
      for (int nf = 0; nf < 4; ++nf)
#pragma unroll
        for (int j = 0; j < 4; ++j)
          C[(size_t)(rbase + mf * 16 + j) * 8192 + cbase + nf * 16] = f2bf(acc[mf][nf][j]);
  } else {
    float* C = (float*)Cv + (size_t)z * sC;
#pragma unroll
    for (int mf = 0; mf < 8; ++mf)
#pragma unroll
      for (int j = 0; j < 4; ++j) {
        float bv = bias[rbase + mf * 16 + j];
#pragma unroll
        for (int nf = 0; nf < 4; ++nf)
          C[(size_t)(rbase + mf * 16 + j) * 8192 + cbase + nf * 16] = acc[mf][nf][j] + bv;
      }
  }
}

// ---------------- context partials: per (split s, h, b): atomically accumulate
// E[b][h][d][e] += exp(k) @ v^T over L-slice, Z[b][h][d] += rowsum(exp(k))
#define NSPLIT 16
#define SLICE  512   // 8192 / NSPLIT
__global__ __launch_bounds__(256) void ctx_partial(const u16* __restrict__ kv,
                                                   float* __restrict__ E, float* __restrict__ Z) {
  int s = blockIdx.x, h = blockIdx.y, b = blockIdx.z;
  int tid = threadIdx.x, wid = tid >> 6, lane = tid & 63;
  int fr = lane & 15, kg = lane >> 4;
  const u16* kbase = kv + ((size_t)b * 1024 + h * 64) * 8192;          // k rows
  const u16* vbase = kbase + (size_t)512 * 8192;                        // v rows
  int d = wid * 16 + fr;                                                // A-frag row for this lane
  const u16* krow = kbase + (size_t)d * 8192 + s * SLICE + kg * 8;
  f32x4 acc[4] = {};
  float z = 0.f;
  for (int l = 0; l < SLICE; l += 32) {
    s16x8 kf = *(const s16x8*)(krow + l);
    s16x8 pf;
#pragma unroll
    for (int j = 0; j < 8; ++j) {
      float p = __expf(bf2f((u16)kf[j]));   // no max-subtraction: |k| <~ 6, exp safe in fp32
      z += p;
      pf[j] = (short)f2bf(p);
    }
#pragma unroll
    for (int ni = 0; ni < 4; ++ni) {
      int e = ni * 16 + fr;
      const s16x8 vf = *(const s16x8*)(vbase + (size_t)e * 8192 + s * SLICE + kg * 8 + l);
      acc[ni] = __builtin_amdgcn_mfma_f32_16x16x32_bf16(pf, vf, acc[ni], 0, 0, 0);
    }
  }
  z += __shfl_xor(z, 16);
  z += __shfl_xor(z, 32);
  size_t bh = (size_t)(b * 8 + h);
  if (kg == 0) atomicAdd(&Z[bh * 64 + d], z);
  float* Eb = E + bh * 4096;
#pragma unroll
  for (int ni = 0; ni < 4; ++ni)
#pragma unroll
    for (int j = 0; j < 4; ++j)
      atomicAdd(&Eb[(wid * 16 + kg * 4 + j) * 64 + ni * 16 + fr], acc[ni][j]);  // C/D: col=l&15, row=(l>>4)*4+j
}

// ---------------- normalize ctx + M1[b][c][h*64+d] = sum_e Wout[c][h*64+e]*ctx[d][e]
__global__ __launch_bounds__(256) void m1_fused(const float* __restrict__ E, const float* __restrict__ Z,
                                                const u16* __restrict__ Wout, u16* __restrict__ M1) {
  int cb = blockIdx.x, h = blockIdx.y, b = blockIdx.z;
  __shared__ float ctx[64][65];
  __shared__ float zs[64];
  int tid = threadIdx.x;
  size_t bh = (size_t)(b * 8 + h);
  const float* Eb = E + bh * 4096;
  if (tid < 64) zs[tid] = Z[bh * 64 + tid];
  __syncthreads();
  for (int i = tid; i < 4096; i += 256)
    ctx[i >> 6][i & 63] = Eb[i] / zs[i >> 6];
  __syncthreads();
  int d = tid & 63;
  int hbase = h * 64;
  for (int ci = 0; ci < 16; ++ci) {
    int c = __builtin_amdgcn_readfirstlane(cb * 64 + (tid >> 6) + ci * 4);  // wave-uniform -> SGPR
    const u16* wrow = Wout + c * 512 + hbase;
    float a0 = 0.f, a1 = 0.f, a2 = 0.f, a3 = 0.f;
#pragma unroll
    for (int e = 0; e < 64; e += 4) {
      a0 += bf2f(wrow[e + 0]) * ctx[d][e + 0];
      a1 += bf2f(wrow[e + 1]) * ctx[d][e + 1];
      a2 += bf2f(wrow[e + 2]) * ctx[d][e + 2];
      a3 += bf2f(wrow[e + 3]) * ctx[d][e + 3];
    }
    M1[((size_t)b * 512 + c) * 512 + hbase + d] = f2bf((a0 + a1) + (a2 + a3));
  }
}

extern "C" void kernel_launch(void* const* d_in, const int* in_sizes, int n_in,
                              void* d_out, int out_size, void* d_ws, size_t ws_size,
                              hipStream_t stream) {
  const float* x     = (const float*)d_in[0];   // [8,512,8192]
  const float* Wqkv  = (const float*)d_in[1];   // [1536,512]
  const float* Woutf = (const float*)d_in[2];   // [512,512]
  const float* bout  = (const float*)d_in[3];   // [512]
  char* ws = (char*)d_ws;
  u16*  xt  = (u16*)ws;                          //  64 MB  xt[b][l][c] bf16
  u16*  kv  = (u16*)(ws + 67108864);             // 128 MB  kv[b][o<1024][l] bf16 (k rows 0..511, v rows 512..1023)
  u16*  Wkv = (u16*)(ws + 201326592);            //   1 MB
  u16*  WqT = (u16*)(ws + 202375168);            // 0.5 MB
  u16*  Wo  = (u16*)(ws + 202899456);            // 0.5 MB
  u16*  M1  = (u16*)(ws + 203423744);            //   4 MB
  u16*  G   = (u16*)(ws + 207618048);            //   4 MB
  float* E  = (float*)(ws + 211812352);          //   1 MB  E[b][h][64][64] f32 (atomic-accumulated)
  float* Z  = (float*)(ws + 212860928);          //  16 KB  Z[b][h][64] f32

  hipMemsetAsync(ws + 211812352, 0, 1048576 + 16384, stream);  // zero E+Z (ws not re-poisoned between replays)
  prep_w<<<2048, 256, 0, stream>>>(Wqkv, Woutf, Wkv, WqT, Wo);
  prep_x<<<dim3(256, 16, 8), 256, 0, stream>>>(x, xt);
  // kv[b] = Wkv @ x[b] : M=1024, N=8192, K=512  (256² 8-phase; grid = Nt*Mt*B = 32*4*8)
  gemm8p<0><<<1024, 512, 0, stream>>>(Wkv, 0, xt, (size_t)8192 * 512,
                                      kv, (size_t)1024 * 8192, nullptr, 4, 32);
  ctx_partial<<<dim3(NSPLIT, 8, 8), 256, 0, stream>>>(kv, E, Z);
  m1_fused<<<dim3(8, 8, 8), 256, 0, stream>>>(E, Z, Wo, M1);
  // G[b] = M1[b] @ Wq : M=512, N=512, K=512   (small: old 128² kernel)
  gemm_bt<<<dim3(4, 4, 8), 256, 0, stream>>>(M1, (size_t)512 * 512, WqT, 0,
                                             G, (size_t)512 * 512, 512, 512);
  // out[b] = G[b] @ x[b] + b_out : M=512, N=8192, K=512, f32 out + bias  (grid = 32*2*8)
  gemm8p<1><<<512, 512, 0, stream>>>(G, (size_t)512 * 512, xt, (size_t)8192 * 512,
                                     d_out, (size_t)512 * 8192, bout, 2, 32);
}